// Round 18
// baseline (783.855 us; speedup 1.0000x reference)
//
#include <hip/hip_runtime.h>
#include <math.h>

#define H 128

typedef __attribute__((ext_vector_type(8))) short short8;
typedef __attribute__((ext_vector_type(4))) float f32x4;

static const int SRC_T_[7] = {0, 0, 1, 1, 1, 2, 2};
static const int DST_T_[7] = {0, 1, 0, 1, 2, 1, 2};

__device__ __forceinline__ float eluf(float x) {
    return x > 0.f ? x : (__expf(x) - 1.f);
}
__device__ __forceinline__ unsigned short f2bf(float x) {  // RNE f32->bf16
    union { float f; unsigned int u; } v; v.f = x;
    unsigned int r = v.u + 0x7fffu + ((v.u >> 16) & 1u);
    return (unsigned short)(r >> 16);
}
__device__ __forceinline__ float bf2f(unsigned int u) {
    union { unsigned int u; float f; } v; v.u = u << 16;
    return v.f;
}

// async global->LDS, 16 bytes per lane; lds base wave-uniform, gsrc per-lane
#define GLDS16(gp, lp) __builtin_amdgcn_global_load_lds( \
    (const __attribute__((address_space(1))) void*)(gp), \
    (__attribute__((address_space(3))) void*)(lp), 16, 0, 0)

// ---------------------------------------------------------------------------
// k_pre: [hist (per-rel block ranges) | weight prep (mlp + input)] — no LDS.
struct PreCtx {
    const int* dst[7];
    int* deg;
    int E[7], bOff[8], hOff[8];
    const float* W1; const float* W2; const float* linW[3];
    unsigned short* wp; unsigned short* wlin;
    int gEnd;
};

__global__ __launch_bounds__(256) void k_pre(PreCtx P)
{
    const int b = blockIdx.x;
    const int tid = threadIdx.x;

    if (b < P.hOff[7]) {                  // ---- histogram ----
        int r = 0;
        while (b >= P.hOff[r + 1]) ++r;
        const int lb = b - P.hOff[r];
        const int nb = P.hOff[r + 1] - P.hOff[r];
        const int* dst = P.dst[r];
        int* degr = P.deg + (P.bOff[r] << 8);
        for (int e = lb * 256 + tid; e < P.E[r]; e += nb * 256)
            atomicAdd(&degr[dst[e]], 1);
        return;
    }
    {                                     // ---- weight prep ----
        const int lb = b - P.hOff[7];
        const int gw = P.gEnd - P.hOff[7];
        for (int i = lb * 256 + tid; i < 21 * 16384; i += gw * 256) {
            int lr = i >> 14, rem = i & 16383;
            int c = rem >> 7, k = rem & 127;
            P.wp[(size_t)(lr * 2 + 0) * 16384 + rem] = f2bf(P.W1[(size_t)lr * 16384 + k * H + c]);
            P.wp[(size_t)(lr * 2 + 1) * 16384 + rem] = f2bf(P.W2[(size_t)lr * 16384 + k * H + c]);
        }
        // input weights: linW[t] [64k][128c] f32 -> wlin [t][128c][64k] bf16
        for (int i = lb * 256 + tid; i < 3 * 8192; i += gw * 256) {
            int t = i >> 13, rem = i & 8191;
            int c = rem >> 6, k = rem & 63;
            P.wlin[t * 8192 + c * 64 + k] = f2bf(P.linW[t][k * H + c]);
        }
    }
}

// ---------------------------------------------------------------------------
// MFMA input embedding: hb[t] = bf16(elu(x @ W + b)); x:[n,64] f32.
struct InCtx {
    const float* x[3]; const float* linb[3];
    unsigned short* hb[3]; int n[3];
    int gend[3];
};

__global__ __launch_bounds__(512, 2) void k_input_mfma(
    InCtx I, const unsigned short* __restrict__ wlin)
{
    __shared__ unsigned short xb[128 * 64];   // 16 KB, XOR-swizzled
    __shared__ unsigned short ob[128 * H];    // 32 KB

    const int b = blockIdx.x;
    const int t = (b >= I.gend[0] ? 1 : 0) + (b >= I.gend[1] ? 1 : 0);
    const int lb = b - (t == 0 ? 0 : I.gend[t - 1]);
    const int n = I.n[t];
    const int tid = threadIdx.x;
    const int lane = tid & 63;
    const int wave = tid >> 6;
    const int wr = wave >> 2;
    const int wc = wave & 3;
    const int l15 = lane & 15;
    const int lq  = lane >> 4;
    const int c0 = wc * 32 + l15;
    const int r0 = lb * 128;
    const int rows = min(128, n - r0);
    const float* x = I.x[t];

    for (int idx = tid; idx < 128 * 16; idx += 512) {
        const int row = idx >> 4, cg = (idx & 15) << 2;
        uint2 p;
        if (row < rows) {
            f32x4 v = *(const f32x4*)&x[(size_t)(r0 + row) * 64 + cg];
            p.x = (unsigned int)f2bf(v.x) | ((unsigned int)f2bf(v.y) << 16);
            p.y = (unsigned int)f2bf(v.z) | ((unsigned int)f2bf(v.w) << 16);
        } else { p.x = 0; p.y = 0; }
        *(uint2*)&xb[row * 64 + (cg ^ ((row & 7) << 3))] = p;
    }
    const unsigned short* wt = wlin + (size_t)t * 8192;
    short8 wf[2][2];
#pragma unroll
    for (int nf = 0; nf < 2; ++nf)
#pragma unroll
        for (int kc = 0; kc < 2; ++kc)
            wf[nf][kc] = *(const short8*)&wt[(c0 + nf * 16) * 64 + kc * 32 + (lq << 3)];
    const float bc0 = I.linb[t][c0], bc1 = I.linb[t][c0 + 16];
    __syncthreads();

    const f32x4 Z4 = {0.f, 0.f, 0.f, 0.f};
    f32x4 acc[4][2];
#pragma unroll
    for (int rb = 0; rb < 4; ++rb)
#pragma unroll
        for (int nf = 0; nf < 2; ++nf) acc[rb][nf] = Z4;
#pragma unroll
    for (int kc = 0; kc < 2; ++kc) {
        const int kb = kc * 32 + (lq << 3);
        short8 af[4];
#pragma unroll
        for (int rb = 0; rb < 4; ++rb) {
            const int row = wr * 64 + rb * 16 + l15;
            af[rb] = *(const short8*)&xb[row * 64 + (kb ^ ((row & 7) << 3))];
        }
#pragma unroll
        for (int rb = 0; rb < 4; ++rb)
#pragma unroll
            for (int nf = 0; nf < 2; ++nf)
                acc[rb][nf] = __builtin_amdgcn_mfma_f32_16x16x32_bf16(
                    af[rb], wf[nf][kc], acc[rb][nf], 0, 0, 0);
    }
#pragma unroll
    for (int rb = 0; rb < 4; ++rb)
#pragma unroll
        for (int nf = 0; nf < 2; ++nf) {
            const int col = c0 + nf * 16;
            const float bc = nf == 0 ? bc0 : bc1;
#pragma unroll
            for (int rg = 0; rg < 4; ++rg) {
                const int row = wr * 64 + rb * 16 + (lq << 2) + rg;
                ob[row * H + col] = f2bf(eluf(acc[rb][nf][rg] + bc));
            }
        }
    __syncthreads();
    uint2* d = (uint2*)&I.hb[t][(size_t)r0 * H];
    const uint2* s2 = (const uint2*)ob;
    for (int idx = tid; idx < rows * 32; idx += 512) d[idx] = s2[idx];
}

// --------------------------- batched CSR build ------------------------------
struct CsrCtx {
    const int* src[7]; const int* dst[7]; const float* ea[7];
    int* csr_src[7]; uint2* csr_ea[7]; int* ptr[7];
    int* deg; int* cursor; int* bsum;
    int eOff[8];
    int bOff[8];
    int nd[7];
};

__global__ __launch_bounds__(256) void k_scan_partial_all(CsrCtx C)
{
    __shared__ int s[256];
    const int b = blockIdx.x;
    int r = 0;
    while (b >= C.bOff[r + 1]) ++r;
    const int lb = b - C.bOff[r];
    const int tid = threadIdx.x;
    const int idx = lb * 256 + tid;
    s[tid] = idx < C.nd[r] ? C.deg[(C.bOff[r] << 8) + idx] : 0;
    __syncthreads();
    for (int off = 128; off > 0; off >>= 1) {
        if (tid < off) s[tid] += s[tid + off];
        __syncthreads();
    }
    if (tid == 0) C.bsum[b] = s[0];
}

__global__ __launch_bounds__(512) void k_scan_mid_all(CsrCtx C)
{
    __shared__ int s[512];
    const int r = blockIdx.x;
    const int nb = C.bOff[r + 1] - C.bOff[r];
    const int tid = threadIdx.x;
    const int v = tid < nb ? C.bsum[C.bOff[r] + tid] : 0;
    s[tid] = v;
    __syncthreads();
    for (int off = 1; off < 512; off <<= 1) {
        int t = (tid >= off) ? s[tid - off] : 0;
        __syncthreads();
        s[tid] += t;
        __syncthreads();
    }
    if (tid < nb) C.bsum[C.bOff[r] + tid] = s[tid] - v;
    if (tid == nb - 1) C.ptr[r][C.nd[r]] = s[tid];
}

__global__ __launch_bounds__(256) void k_scan_final_all(CsrCtx C)
{
    __shared__ int s[256];
    const int b = blockIdx.x;
    int r = 0;
    while (b >= C.bOff[r + 1]) ++r;
    const int lb = b - C.bOff[r];
    const int tid = threadIdx.x;
    const int idx = lb * 256 + tid;
    const int v = idx < C.nd[r] ? C.deg[(C.bOff[r] << 8) + idx] : 0;
    s[tid] = v;
    __syncthreads();
    for (int off = 1; off < 256; off <<= 1) {
        int t = (tid >= off) ? s[tid - off] : 0;
        __syncthreads();
        s[tid] += t;
        __syncthreads();
    }
    if (idx < C.nd[r]) {
        const int excl = s[tid] - v + C.bsum[b];
        C.ptr[r][idx] = excl;
        C.cursor[(C.bOff[r] << 8) + idx] = excl;
    }
}

__global__ __launch_bounds__(256) void k_scatter_all(CsrCtx C, int Etot)
{
    for (int e = blockIdx.x * 256 + threadIdx.x; e < Etot; e += gridDim.x * 256) {
        int r = 0;
        while (e >= C.eOff[r + 1]) ++r;
        const int le = e - C.eOff[r];
        const int d = C.dst[r][le];
        const int pos = atomicAdd(&C.cursor[(C.bOff[r] << 8) + d], 1);
        C.csr_src[r][pos] = C.src[r][le];
        const float* eap = C.ea[r] + (size_t)3 * le;
        uint2 p;
        p.x = (unsigned int)f2bf(eap[0]) | ((unsigned int)f2bf(eap[1]) << 16);
        p.y = (unsigned int)f2bf(eap[2]);
        C.csr_ea[r][pos] = p;
    }
}

// ---------------------------------------------------------------------------
// Batched gather-aggregate: per-relation block ranges; 4 waves/block;
// wave = 16 consecutive nodes, full wave per node (2 cols/lane).
// Node-level + edge-level software pipeline.
// z written PRE-SWIZZLED (uint idx ^ (d&7)<<2).
struct AggCtx {
    const int* ptr[7]; const int* csr_src[7]; const uint2* csr_ea[7];
    const unsigned short* hsrc[7]; const unsigned short* hdst[7];
    unsigned short* z[7];
    int gOff[8];
    int nd[7];
};

__global__ __launch_bounds__(256) void k_aggz_all(
    AggCtx A, const float* __restrict__ eW, const float* __restrict__ eb, int l)
{
    const int b = blockIdx.x;
    int r = 0;
    while (b >= A.gOff[r + 1]) ++r;
    const int lb = b - A.gOff[r];
    const int wave = threadIdx.x >> 6;
    const int lane = threadIdx.x & 63;
    const int t2 = lane << 1;
    const int lr = l * 7 + r;
    const float* eWr = eW + (size_t)lr * 3 * H;
    const float* ebr = eb + (size_t)lr * H;
    const float w00 = eWr[t2],         w01 = eWr[t2 + 1];
    const float w10 = eWr[H + t2],     w11 = eWr[H + t2 + 1];
    const float w20 = eWr[2 * H + t2], w21 = eWr[2 * H + t2 + 1];
    const float b0 = ebr[t2], b1v = ebr[t2 + 1];

    const int nd = A.nd[r];
    const int d0 = lb * 64 + wave * 16;
    if (d0 >= nd) return;
    const int dend = min(d0 + 16, nd);
    const int* __restrict__ ptr = A.ptr[r];
    const int* __restrict__ cs = A.csr_src[r];
    const uint2* __restrict__ ce = A.csr_ea[r];
    const unsigned short* __restrict__ hs = A.hsrc[r];
    const unsigned short* __restrict__ hd = A.hdst[r];
    unsigned int* __restrict__ zp = (unsigned int*)A.z[r];

    int pA = ptr[d0];
    int pB = ptr[d0 + 1];
    unsigned int hdvC = ((const unsigned int*)&hd[(size_t)d0 * H])[lane];

    for (int d = d0; d < dend; ++d) {
        int pNext = 0; unsigned int hdvN = 0;
        if (d + 1 < dend) {
            pNext = ptr[d + 2];
            hdvN = ((const unsigned int*)&hd[(size_t)(d + 1) * H])[lane];
        }
        float acc0 = bf2f(hdvC & 0xffffu);
        float acc1 = bf2f(hdvC >> 16);
        int i = pA;
        const int p1 = pB;
        if (i + 1 < p1) {
            int s0 = cs[i], s1 = cs[i + 1];
            uint2 eC0 = ce[i], eC1 = ce[i + 1];
            unsigned int hvC0 = ((const unsigned int*)&hs[(size_t)s0 * H])[lane];
            unsigned int hvC1 = ((const unsigned int*)&hs[(size_t)s1 * H])[lane];
            for (;;) {
                const int jn = i + 2;
                const bool more = (jn + 1 < p1);
                uint2 eN0, eN1; unsigned int hvN0 = 0, hvN1 = 0;
                if (more) {
                    const int sN0 = cs[jn], sN1 = cs[jn + 1];
                    eN0 = ce[jn]; eN1 = ce[jn + 1];
                    hvN0 = ((const unsigned int*)&hs[(size_t)sN0 * H])[lane];
                    hvN1 = ((const unsigned int*)&hs[(size_t)sN1 * H])[lane];
                }
                const float a00 = bf2f(eC0.x & 0xffffu), a01 = bf2f(eC0.x >> 16), a02 = bf2f(eC0.y & 0xffffu);
                const float a10 = bf2f(eC1.x & 0xffffu), a11 = bf2f(eC1.x >> 16), a12 = bf2f(eC1.y & 0xffffu);
                acc0 += fmaxf(bf2f(hvC0 & 0xffffu) + a00 * w00 + a01 * w10 + a02 * w20 + b0, 0.f)
                      + fmaxf(bf2f(hvC1 & 0xffffu) + a10 * w00 + a11 * w10 + a12 * w20 + b0, 0.f);
                acc1 += fmaxf(bf2f(hvC0 >> 16) + a00 * w01 + a01 * w11 + a02 * w21 + b1v, 0.f)
                      + fmaxf(bf2f(hvC1 >> 16) + a10 * w01 + a11 * w11 + a12 * w21 + b1v, 0.f);
                i = jn;
                if (!more) break;
                eC0 = eN0; eC1 = eN1; hvC0 = hvN0; hvC1 = hvN1;
            }
        }
        if (i < p1) {  // odd tail
            const int s = cs[i];
            const uint2 ep = ce[i];
            const float a0 = bf2f(ep.x & 0xffffu);
            const float a1 = bf2f(ep.x >> 16);
            const float a2 = bf2f(ep.y & 0xffffu);
            const unsigned int hv = ((const unsigned int*)&hs[(size_t)s * H])[lane];
            acc0 += fmaxf(bf2f(hv & 0xffffu) + a0 * w00 + a1 * w10 + a2 * w20 + b0, 0.f);
            acc1 += fmaxf(bf2f(hv >> 16)     + a0 * w01 + a1 * w11 + a2 * w21 + b1v, 0.f);
        }
        zp[(size_t)d * 64 + (lane ^ ((d & 7) << 2))] =
            (unsigned int)f2bf(acc0) | ((unsigned int)f2bf(acc1) << 16);
        pA = pB; pB = pNext; hdvC = hdvN;
    }
}

// ---------------------------------------------------------------------------
// Persistent fused MLP: 512 blocks, partitioned per type; each block loops
// over its type's tiles (stride nb[t]). Cross-tile prefetch: next tile's
// rel0 z staged at last relation's barrier B (flies under GEMM2+epilogue).
// fin layer stages cold (epilogue reuses all 64 KB LDS).
struct MlpCtx {
    const unsigned short* z[3][3];
    int lr[3][3];
    int nrel[3];
    int pend[3];     // block-partition ends
    int ntile[3];    // 128-row tiles per type
    int noffH[3];
    int n[3];
};

__global__ __launch_bounds__(512, 2) void k_mlp_all(
    MlpCtx M, const unsigned short* __restrict__ hb,
    unsigned short* __restrict__ hbw, float* __restrict__ fout,
    const unsigned short* __restrict__ wprep,
    const float* __restrict__ b1g, const float* __restrict__ g1g,
    const float* __restrict__ be1g, const float* __restrict__ b2g, int fin)
{
    __shared__ unsigned short smem[2 * 128 * H];   // 64 KB
    unsigned short* zt  = smem;
    unsigned short* a1t = smem + 128 * H;

    const int b = blockIdx.x;
    const int t = (b >= M.pend[0] ? 1 : 0) + (b >= M.pend[1] ? 1 : 0);
    const int lb = b - (t == 0 ? 0 : M.pend[t - 1]);
    const int nbt = M.pend[t] - (t == 0 ? 0 : M.pend[t - 1]);
    const int ntl = M.ntile[t];
    if (lb >= ntl) return;
    const int n = M.n[t];
    const int nrel = M.nrel[t];
    const unsigned short* hbp = hb + (size_t)M.noffH[t];

    const int tid = threadIdx.x;
    const int lane = tid & 63;
    const int wave = tid >> 6;
    const int wr = wave >> 2;
    const int wc = wave & 3;
    const int l15 = lane & 15;
    const int lq  = lane >> 4;
    const int c0 = wc * 32 + l15;

    const float bn_inv = 0.99999500003749977f;
    const f32x4 Z4 = {0.f, 0.f, 0.f, 0.f};

    // stage a z tile (rows rows starting at row0) into zt
    auto stage = [&](const unsigned short* z, int row0, int nrows) {
        const unsigned short* zsrc = z + (size_t)row0 * H;
        if (nrows == 128) {
#pragma unroll
            for (int it = 0; it < 4; ++it) {
                const int off = (wave * 4 + it) * 512;
                GLDS16(zsrc + off + lane * 8, zt + off);
            }
        } else {
            for (int idx = tid; idx < nrows * 16; idx += 512) {
                *(uint4*)&zt[idx * 8] = *(const uint4*)&zsrc[idx * 8];
            }
        }
    };

    bool prefetched = false;
    for (int tile = lb; tile < ntl; tile += nbt) {
        const int r0 = tile * 128;
        const int rows = min(128, n - r0);
        if (!prefetched) stage(M.z[t][0], r0, rows);
        prefetched = false;

        f32x4 acc2[4][2];
#pragma unroll
        for (int rb = 0; rb < 4; ++rb)
#pragma unroll
            for (int nf = 0; nf < 2; ++nf) acc2[rb][nf] = Z4;
        float b2s0 = 0.f, b2s1 = 0.f;

        for (int rl = 0; rl < nrel; ++rl) {
            const int lr = M.lr[t][rl];
            const unsigned short* wp = wprep + (size_t)lr * 32768;
            short8 w1f[2][4], w2f[2][4];
#pragma unroll
            for (int nf = 0; nf < 2; ++nf)
#pragma unroll
                for (int kc = 0; kc < 4; ++kc) {
                    w1f[nf][kc] = *(const short8*)&wp[(c0 + nf * 16) * H + kc * 32 + (lq << 3)];
                    w2f[nf][kc] = *(const short8*)&wp[16384 + (c0 + nf * 16) * H + kc * 32 + (lq << 3)];
                }
            const float b1c0 = b1g[lr * H + c0],            b1c1 = b1g[lr * H + c0 + 16];
            const float sc0  = g1g[lr * H + c0] * bn_inv,   sc1  = g1g[lr * H + c0 + 16] * bn_inv;
            const float be0  = be1g[lr * H + c0],           be1v = be1g[lr * H + c0 + 16];
            b2s0 += b2g[lr * H + c0]; b2s1 += b2g[lr * H + c0 + 16];

            __syncthreads();  // A: drains staging -> zt ready

            f32x4 acc1[4][2];
#pragma unroll
            for (int rb = 0; rb < 4; ++rb)
#pragma unroll
                for (int nf = 0; nf < 2; ++nf) acc1[rb][nf] = Z4;
#pragma unroll
            for (int kc = 0; kc < 4; ++kc) {
                const int kb = kc * 32 + (lq << 3);
                short8 af[4];
#pragma unroll
                for (int rb = 0; rb < 4; ++rb) {
                    const int row = wr * 64 + rb * 16 + l15;
                    af[rb] = *(const short8*)&zt[row * H + (kb ^ ((row & 7) << 3))];
                }
#pragma unroll
                for (int rb = 0; rb < 4; ++rb)
#pragma unroll
                    for (int nf = 0; nf < 2; ++nf)
                        acc1[rb][nf] = __builtin_amdgcn_mfma_f32_16x16x32_bf16(
                            af[rb], w1f[nf][kc], acc1[rb][nf], 0, 0, 0);
            }
#pragma unroll
            for (int rb = 0; rb < 4; ++rb)
#pragma unroll
                for (int nf = 0; nf < 2; ++nf) {
                    const int col = c0 + nf * 16;
                    const float b1c = nf == 0 ? b1c0 : b1c1;
                    const float scv = nf == 0 ? sc0 : sc1;
                    const float bev = nf == 0 ? be0 : be1v;
#pragma unroll
                    for (int rg = 0; rg < 4; ++rg) {
                        const int row = wr * 64 + rb * 16 + (lq << 2) + rg;
                        float v = fmaxf((acc1[rb][nf][rg] + b1c) * scv + bev, 0.f);
                        a1t[row * H + (col ^ ((row & 7) << 3))] = f2bf(v);
                    }
                }
            __syncthreads();  // B: a1t ready; zt dead

            if (rl + 1 < nrel) {
                stage(M.z[t][rl + 1], r0, rows);
            } else if (!fin && tile + nbt < ntl) {
                const int r0n = (tile + nbt) * 128;
                stage(M.z[t][0], r0n, min(128, n - r0n));
                prefetched = true;
            }

#pragma unroll
            for (int kc = 0; kc < 4; ++kc) {
                const int kb = kc * 32 + (lq << 3);
                short8 af[4];
#pragma unroll
                for (int rb = 0; rb < 4; ++rb) {
                    const int row = wr * 64 + rb * 16 + l15;
                    af[rb] = *(const short8*)&a1t[row * H + (kb ^ ((row & 7) << 3))];
                }
#pragma unroll
                for (int rb = 0; rb < 4; ++rb)
#pragma unroll
                    for (int nf = 0; nf < 2; ++nf)
                        acc2[rb][nf] = __builtin_amdgcn_mfma_f32_16x16x32_bf16(
                            af[rb], w2f[nf][kc], acc2[rb][nf], 0, 0, 0);
            }
        }

        if (fin) {
            float* fb = (float*)smem;
            float* foutp = fout + (size_t)M.noffH[t];
            __syncthreads();
#pragma unroll
            for (int rb = 0; rb < 4; ++rb)
#pragma unroll
                for (int nf = 0; nf < 2; ++nf) {
                    const int col = c0 + nf * 16;
                    const float b2s = nf == 0 ? b2s0 : b2s1;
#pragma unroll
                    for (int rg = 0; rg < 4; ++rg) {
                        const int row = wr * 64 + rb * 16 + (lq << 2) + rg;
                        if (row < rows) {
                            const size_t o = (size_t)(r0 + row) * H + col;
                            fb[row * H + col] = eluf(acc2[rb][nf][rg] + b2s
                                                     + bf2f((unsigned int)hbp[o]));
                        }
                    }
                }
            __syncthreads();
            float4* d4 = (float4*)&foutp[(size_t)r0 * H];
            const float4* s4 = (const float4*)fb;
            for (int idx = tid; idx < rows * 32; idx += 512) d4[idx] = s4[idx];
            __syncthreads();  // fb (zt+a1t) free before next tile's stage
        } else {
            unsigned short* hbwp = hbw + (size_t)M.noffH[t];
            __syncthreads();
#pragma unroll
            for (int rb = 0; rb < 4; ++rb)
#pragma unroll
                for (int nf = 0; nf < 2; ++nf) {
                    const int col = c0 + nf * 16;
                    const float b2s = nf == 0 ? b2s0 : b2s1;
#pragma unroll
                    for (int rg = 0; rg < 4; ++rg) {
                        const int row = wr * 64 + rb * 16 + (lq << 2) + rg;
                        if (row < rows) {
                            const size_t o = (size_t)(r0 + row) * H + col;
                            a1t[row * H + col] = f2bf(eluf(acc2[rb][nf][rg] + b2s
                                                           + bf2f((unsigned int)hbp[o])));
                        }
                    }
                }
            __syncthreads();
            uint2* d = (uint2*)&hbwp[(size_t)r0 * H];
            const uint2* s2 = (const uint2*)a1t;
            for (int idx = tid; idx < rows * 32; idx += 512) d[idx] = s2[idx];
            // no extra barrier: next tile's first barrier A fences a1t reuse
        }
    }
}

static inline int imin(int a, int b) { return a < b ? a : b; }
static inline int imax(int a, int b) { return a > b ? a : b; }
static inline size_t alignup(size_t x) { return (x + 255) & ~(size_t)255; }

extern "C" void kernel_launch(void* const* d_in, const int* in_sizes, int n_in,
                              void* d_out, int out_size, void* d_ws, size_t ws_size,
                              hipStream_t stream) {
    const float* xin[3] = {(const float*)d_in[0], (const float*)d_in[1], (const float*)d_in[2]};
    const int* src[7]; const int* dst[7]; const float* ea[7]; int E[7];
    for (int r = 0; r < 7; ++r) {
        src[r] = (const int*)d_in[3 + 3 * r];
        dst[r] = (const int*)d_in[4 + 3 * r];
        ea[r]  = (const float*)d_in[5 + 3 * r];
        E[r]   = in_sizes[3 + 3 * r];
    }
    const float* linW[3] = {(const float*)d_in[24], (const float*)d_in[26], (const float*)d_in[28]};
    const float* linb[3] = {(const float*)d_in[25], (const float*)d_in[27], (const float*)d_in[29]};
    const float* eW  = (const float*)d_in[30];
    const float* ebp = (const float*)d_in[31];
    const float* W1  = (const float*)d_in[32];
    const float* b1  = (const float*)d_in[33];
    const float* g1  = (const float*)d_in[34];
    const float* be1 = (const float*)d_in[35];
    const float* W2  = (const float*)d_in[36];
    const float* b2  = (const float*)d_in[37];

    const int NSn[3]  = {in_sizes[0] / 64, in_sizes[1] / 64, in_sizes[2] / 64};
    const int NTOT = NSn[0] + NSn[1] + NSn[2];
    const int noff[3] = {0, NSn[0], NSn[0] + NSn[1]};

    float* fout = (float*)d_out;

    // prefixes
    int eOff[8]; eOff[0] = 0;
    for (int r = 0; r < 7; ++r) eOff[r + 1] = eOff[r] + E[r];
    const int Etot = eOff[7];
    int bOff[8]; bOff[0] = 0;
    for (int r = 0; r < 7; ++r) bOff[r + 1] = bOff[r] + (NSn[DST_T_[r]] + 255) / 256;
    int gOff[8]; gOff[0] = 0;
    for (int r = 0; r < 7; ++r) gOff[r + 1] = gOff[r] + (NSn[DST_T_[r]] + 63) / 64;

    // workspace carve-up
    char* wsb = (char*)d_ws;
    size_t off = 0;
    unsigned short* hb = (unsigned short*)(wsb + off); off = alignup(off + (size_t)NTOT * H * 2);
    unsigned short* zb[7];
    for (int r = 0; r < 7; ++r) {
        int nd = NSn[DST_T_[r]];
        zb[r] = (unsigned short*)(wsb + off); off = alignup(off + (size_t)nd * H * 2);
    }
    unsigned short* wprep = (unsigned short*)(wsb + off); off = alignup(off + (size_t)21 * 32768 * 2);
    unsigned short* wlin  = (unsigned short*)(wsb + off); off = alignup(off + (size_t)3 * 8192 * 2);
    int* deg    = (int*)(wsb + off); off = alignup(off + (size_t)bOff[7] * 256 * 4);
    int* cursor = (int*)(wsb + off); off = alignup(off + (size_t)bOff[7] * 256 * 4);
    int* bsum   = (int*)(wsb + off); off = alignup(off + (size_t)bOff[7] * 4 + 256);
    int* ptrs[7]; int* csrs[7]; uint2* ceas[7];
    for (int r = 0; r < 7; ++r) {
        int nd = NSn[DST_T_[r]];
        ptrs[r] = (int*)(wsb + off); off = alignup(off + (size_t)(nd + 1) * 4);
    }
    for (int r = 0; r < 7; ++r) {
        csrs[r] = (int*)(wsb + off); off = alignup(off + (size_t)E[r] * 4);
    }
    for (int r = 0; r < 7; ++r) {
        ceas[r] = (uint2*)(wsb + off); off = alignup(off + (size_t)E[r] * 8);
    }

    // ---- preamble: hist + weight prep ----
    PreCtx P;
    for (int r = 0; r < 7; ++r) { P.dst[r] = dst[r]; P.E[r] = E[r]; }
    P.deg = deg;
    for (int r = 0; r < 8; ++r) P.bOff[r] = bOff[r];
    P.hOff[0] = 0;
    for (int r = 0; r < 7; ++r)
        P.hOff[r + 1] = P.hOff[r] + imax(1, (E[r] + 1023) / 1024);
    P.W1 = W1; P.W2 = W2; P.wp = wprep; P.wlin = wlin;
    for (int t = 0; t < 3; ++t) P.linW[t] = linW[t];
    P.gEnd = P.hOff[7] + 256;

    hipMemsetAsync(deg, 0, (size_t)bOff[7] * 256 * 4, stream);
    k_pre<<<P.gEnd, 256, 0, stream>>>(P);

    // ---- MFMA input embedding ----
    InCtx I;
    int ig = 0;
    for (int t = 0; t < 3; ++t) {
        I.x[t] = xin[t]; I.linb[t] = linb[t];
        I.hb[t] = hb + (size_t)noff[t] * H; I.n[t] = NSn[t];
        ig += (NSn[t] + 127) / 128;
        I.gend[t] = ig;
    }
    k_input_mfma<<<ig, 512, 0, stream>>>(I, wlin);

    // ---- CSR scans + scatter ----
    CsrCtx C;
    for (int r = 0; r < 7; ++r) {
        C.src[r] = src[r]; C.dst[r] = dst[r]; C.ea[r] = ea[r];
        C.csr_src[r] = csrs[r]; C.csr_ea[r] = ceas[r]; C.ptr[r] = ptrs[r];
        C.nd[r] = NSn[DST_T_[r]];
    }
    C.deg = deg; C.cursor = cursor; C.bsum = bsum;
    for (int r = 0; r < 8; ++r) { C.eOff[r] = eOff[r]; C.bOff[r] = bOff[r]; }

    k_scan_partial_all<<<bOff[7], 256, 0, stream>>>(C);
    k_scan_mid_all<<<7, 512, 0, stream>>>(C);
    k_scan_final_all<<<bOff[7], 256, 0, stream>>>(C);
    k_scatter_all<<<imin((Etot + 255) / 256, 8192), 256, 0, stream>>>(C, Etot);

    // ---- agg context ----
    AggCtx A;
    for (int r = 0; r < 7; ++r) {
        A.ptr[r] = ptrs[r]; A.csr_src[r] = csrs[r]; A.csr_ea[r] = ceas[r];
        A.hsrc[r] = hb + (size_t)noff[SRC_T_[r]] * H;
        A.hdst[r] = hb + (size_t)noff[DST_T_[r]] * H;
        A.z[r] = zb[r];
        A.nd[r] = NSn[DST_T_[r]];
    }
    for (int r = 0; r < 8; ++r) A.gOff[r] = gOff[r];

    // ---- mlp context (persistent blocks) ----
    static const int RELS[3][3] = {{0, 2, 0}, {1, 3, 5}, {4, 6, 0}};
    static const int NRELS[3] = {2, 3, 2};
    MlpCtx M;
    int tiles[3], ttot = 0;
    for (int t = 0; t < 3; ++t) { tiles[t] = (NSn[t] + 127) / 128; ttot += tiles[t]; }
    int pend = 0;
    for (int t = 0; t < 3; ++t) {
        M.nrel[t] = NRELS[t];
        M.noffH[t] = noff[t] * H;
        M.n[t] = NSn[t];
        M.ntile[t] = tiles[t];
        int nb = imax(1, (int)((long long)512 * tiles[t] / ttot));
        nb = imin(nb, tiles[t]);
        pend += nb;
        M.pend[t] = pend;
        for (int k = 0; k < 3; ++k) M.z[t][k] = zb[RELS[t][k]];
    }

    // ---- layers ----
    for (int l = 0; l < 3; ++l) {
        const int fin = (l == 2) ? 1 : 0;
        k_aggz_all<<<gOff[7], 256, 0, stream>>>(A, eW, ebp, l);
        for (int t = 0; t < 3; ++t)
            for (int k = 0; k < 3; ++k) M.lr[t][k] = l * 7 + RELS[t][k];
        k_mlp_all<<<M.pend[2], 512, 0, stream>>>(
            M, hb, hb, fout, wprep, b1, g1, be1, b2, fin);
    }
}

// Round 19
// 783.591 us; speedup vs baseline: 1.0003x; 1.0003x over previous
//
#include <hip/hip_runtime.h>
#include <math.h>

#define H 128

typedef __attribute__((ext_vector_type(8))) short short8;
typedef __attribute__((ext_vector_type(4))) float f32x4;

static const int SRC_T_[7] = {0, 0, 1, 1, 1, 2, 2};
static const int DST_T_[7] = {0, 1, 0, 1, 2, 1, 2};

__device__ __forceinline__ float eluf(float x) {
    return x > 0.f ? x : (__expf(x) - 1.f);
}
__device__ __forceinline__ unsigned short f2bf(float x) {  // RNE f32->bf16
    union { float f; unsigned int u; } v; v.f = x;
    unsigned int r = v.u + 0x7fffu + ((v.u >> 16) & 1u);
    return (unsigned short)(r >> 16);
}
__device__ __forceinline__ float bf2f(unsigned int u) {
    union { unsigned int u; float f; } v; v.u = u << 16;
    return v.f;
}

// async global->LDS, 16 bytes per lane; lds base wave-uniform, gsrc per-lane
#define GLDS16(gp, lp) __builtin_amdgcn_global_load_lds( \
    (const __attribute__((address_space(1))) void*)(gp), \
    (__attribute__((address_space(3))) void*)(lp), 16, 0, 0)

// ---------------------------------------------------------------------------
// k_pre: [hist (per-rel block ranges) | weight prep (mlp + input)] — no LDS.
struct PreCtx {
    const int* dst[7];
    int* deg;
    int E[7], bOff[8], hOff[8];
    const float* W1; const float* W2; const float* linW[3];
    unsigned short* wp; unsigned short* wlin;
    int gEnd;
};

__global__ __launch_bounds__(256) void k_pre(PreCtx P)
{
    const int b = blockIdx.x;
    const int tid = threadIdx.x;

    if (b < P.hOff[7]) {                  // ---- histogram ----
        int r = 0;
        while (b >= P.hOff[r + 1]) ++r;
        const int lb = b - P.hOff[r];
        const int nb = P.hOff[r + 1] - P.hOff[r];
        const int* dst = P.dst[r];
        int* degr = P.deg + (P.bOff[r] << 8);
        for (int e = lb * 256 + tid; e < P.E[r]; e += nb * 256)
            atomicAdd(&degr[dst[e]], 1);
        return;
    }
    {                                     // ---- weight prep ----
        const int lb = b - P.hOff[7];
        const int gw = P.gEnd - P.hOff[7];
        for (int i = lb * 256 + tid; i < 21 * 16384; i += gw * 256) {
            int lr = i >> 14, rem = i & 16383;
            int c = rem >> 7, k = rem & 127;
            P.wp[(size_t)(lr * 2 + 0) * 16384 + rem] = f2bf(P.W1[(size_t)lr * 16384 + k * H + c]);
            P.wp[(size_t)(lr * 2 + 1) * 16384 + rem] = f2bf(P.W2[(size_t)lr * 16384 + k * H + c]);
        }
        // input weights: linW[t] [64k][128c] f32 -> wlin [t][128c][64k] bf16
        for (int i = lb * 256 + tid; i < 3 * 8192; i += gw * 256) {
            int t = i >> 13, rem = i & 8191;
            int c = rem >> 6, k = rem & 63;
            P.wlin[t * 8192 + c * 64 + k] = f2bf(P.linW[t][k * H + c]);
        }
    }
}

// ---------------------------------------------------------------------------
// MFMA input embedding: hb[t] = bf16(elu(x @ W + b)); x:[n,64] f32.
struct InCtx {
    const float* x[3]; const float* linb[3];
    unsigned short* hb[3]; int n[3];
    int gend[3];
};

__global__ __launch_bounds__(512, 2) void k_input_mfma(
    InCtx I, const unsigned short* __restrict__ wlin)
{
    __shared__ unsigned short xb[128 * 64];   // 16 KB, XOR-swizzled
    __shared__ unsigned short ob[128 * H];    // 32 KB

    const int b = blockIdx.x;
    const int t = (b >= I.gend[0] ? 1 : 0) + (b >= I.gend[1] ? 1 : 0);
    const int lb = b - (t == 0 ? 0 : I.gend[t - 1]);
    const int n = I.n[t];
    const int tid = threadIdx.x;
    const int lane = tid & 63;
    const int wave = tid >> 6;
    const int wr = wave >> 2;
    const int wc = wave & 3;
    const int l15 = lane & 15;
    const int lq  = lane >> 4;
    const int c0 = wc * 32 + l15;
    const int r0 = lb * 128;
    const int rows = min(128, n - r0);
    const float* x = I.x[t];

    for (int idx = tid; idx < 128 * 16; idx += 512) {
        const int row = idx >> 4, cg = (idx & 15) << 2;
        uint2 p;
        if (row < rows) {
            f32x4 v = *(const f32x4*)&x[(size_t)(r0 + row) * 64 + cg];
            p.x = (unsigned int)f2bf(v.x) | ((unsigned int)f2bf(v.y) << 16);
            p.y = (unsigned int)f2bf(v.z) | ((unsigned int)f2bf(v.w) << 16);
        } else { p.x = 0; p.y = 0; }
        *(uint2*)&xb[row * 64 + (cg ^ ((row & 7) << 3))] = p;
    }
    const unsigned short* wt = wlin + (size_t)t * 8192;
    short8 wf[2][2];
#pragma unroll
    for (int nf = 0; nf < 2; ++nf)
#pragma unroll
        for (int kc = 0; kc < 2; ++kc)
            wf[nf][kc] = *(const short8*)&wt[(c0 + nf * 16) * 64 + kc * 32 + (lq << 3)];
    const float bc0 = I.linb[t][c0], bc1 = I.linb[t][c0 + 16];
    __syncthreads();

    const f32x4 Z4 = {0.f, 0.f, 0.f, 0.f};
    f32x4 acc[4][2];
#pragma unroll
    for (int rb = 0; rb < 4; ++rb)
#pragma unroll
        for (int nf = 0; nf < 2; ++nf) acc[rb][nf] = Z4;
#pragma unroll
    for (int kc = 0; kc < 2; ++kc) {
        const int kb = kc * 32 + (lq << 3);
        short8 af[4];
#pragma unroll
        for (int rb = 0; rb < 4; ++rb) {
            const int row = wr * 64 + rb * 16 + l15;
            af[rb] = *(const short8*)&xb[row * 64 + (kb ^ ((row & 7) << 3))];
        }
#pragma unroll
        for (int rb = 0; rb < 4; ++rb)
#pragma unroll
            for (int nf = 0; nf < 2; ++nf)
                acc[rb][nf] = __builtin_amdgcn_mfma_f32_16x16x32_bf16(
                    af[rb], wf[nf][kc], acc[rb][nf], 0, 0, 0);
    }
#pragma unroll
    for (int rb = 0; rb < 4; ++rb)
#pragma unroll
        for (int nf = 0; nf < 2; ++nf) {
            const int col = c0 + nf * 16;
            const float bc = nf == 0 ? bc0 : bc1;
#pragma unroll
            for (int rg = 0; rg < 4; ++rg) {
                const int row = wr * 64 + rb * 16 + (lq << 2) + rg;
                ob[row * H + col] = f2bf(eluf(acc[rb][nf][rg] + bc));
            }
        }
    __syncthreads();
    uint2* d = (uint2*)&I.hb[t][(size_t)r0 * H];
    const uint2* s2 = (const uint2*)ob;
    for (int idx = tid; idx < rows * 32; idx += 512) d[idx] = s2[idx];
}

// --------------------------- batched CSR build ------------------------------
struct CsrCtx {
    const int* src[7]; const int* dst[7]; const float* ea[7];
    uint4* csr_rec[7]; int* ptr[7];
    int* deg; int* cursor; int* bsum;
    int E[7];
    int bOff[8];
    int sOff[8];     // scatter block ranges
    int nd[7];
};

__global__ __launch_bounds__(256) void k_scan_partial_all(CsrCtx C)
{
    __shared__ int s[256];
    const int b = blockIdx.x;
    int r = 0;
    while (b >= C.bOff[r + 1]) ++r;
    const int lb = b - C.bOff[r];
    const int tid = threadIdx.x;
    const int idx = lb * 256 + tid;
    s[tid] = idx < C.nd[r] ? C.deg[(C.bOff[r] << 8) + idx] : 0;
    __syncthreads();
    for (int off = 128; off > 0; off >>= 1) {
        if (tid < off) s[tid] += s[tid + off];
        __syncthreads();
    }
    if (tid == 0) C.bsum[b] = s[0];
}

__global__ __launch_bounds__(512) void k_scan_mid_all(CsrCtx C)
{
    __shared__ int s[512];
    const int r = blockIdx.x;
    const int nb = C.bOff[r + 1] - C.bOff[r];
    const int tid = threadIdx.x;
    const int v = tid < nb ? C.bsum[C.bOff[r] + tid] : 0;
    s[tid] = v;
    __syncthreads();
    for (int off = 1; off < 512; off <<= 1) {
        int t = (tid >= off) ? s[tid - off] : 0;
        __syncthreads();
        s[tid] += t;
        __syncthreads();
    }
    if (tid < nb) C.bsum[C.bOff[r] + tid] = s[tid] - v;
    if (tid == nb - 1) C.ptr[r][C.nd[r]] = s[tid];
}

__global__ __launch_bounds__(256) void k_scan_final_all(CsrCtx C)
{
    __shared__ int s[256];
    const int b = blockIdx.x;
    int r = 0;
    while (b >= C.bOff[r + 1]) ++r;
    const int lb = b - C.bOff[r];
    const int tid = threadIdx.x;
    const int idx = lb * 256 + tid;
    const int v = idx < C.nd[r] ? C.deg[(C.bOff[r] << 8) + idx] : 0;
    s[tid] = v;
    __syncthreads();
    for (int off = 1; off < 256; off <<= 1) {
        int t = (tid >= off) ? s[tid - off] : 0;
        __syncthreads();
        s[tid] += t;
        __syncthreads();
    }
    if (idx < C.nd[r]) {
        const int excl = s[tid] - v + C.bsum[b];
        C.ptr[r][idx] = excl;
        C.cursor[(C.bOff[r] << 8) + idx] = excl;
    }
}

// scatter: per-relation block ranges; packed 16B record {src, ea01, ea2, 0}
__global__ __launch_bounds__(256) void k_scatter_all(CsrCtx C)
{
    const int b = blockIdx.x;
    int r = 0;
    while (b >= C.sOff[r + 1]) ++r;
    const int lb = b - C.sOff[r];
    const int nb = C.sOff[r + 1] - C.sOff[r];
    const int* src = C.src[r];
    const int* dst = C.dst[r];
    const float* ea = C.ea[r];
    int* cur = C.cursor + (C.bOff[r] << 8);
    uint4* rec = C.csr_rec[r];
    for (int e = lb * 256 + threadIdx.x; e < C.E[r]; e += nb * 256) {
        const int d = dst[e];
        const int pos = atomicAdd(&cur[d], 1);
        const float* eap = ea + (size_t)3 * e;
        uint4 p;
        p.x = (unsigned int)src[e];
        p.y = (unsigned int)f2bf(eap[0]) | ((unsigned int)f2bf(eap[1]) << 16);
        p.z = (unsigned int)f2bf(eap[2]);
        p.w = 0;
        rec[pos] = p;
    }
}

// ---------------------------------------------------------------------------
// Batched gather-aggregate: per-relation block ranges; 4 waves/block;
// wave = 16 consecutive nodes, full wave per node (2 cols/lane).
// 4-wide predicated edge processing on packed 16B records: all 4 record
// loads + 4 row gathers in flight per iteration (deg<=4 nodes = 1 iter).
// z written PRE-SWIZZLED (uint idx ^ (d&7)<<2).
struct AggCtx {
    const int* ptr[7]; const uint4* csr_rec[7];
    const unsigned short* hsrc[7]; const unsigned short* hdst[7];
    unsigned short* z[7];
    int gOff[8];
    int nd[7];
};

__global__ __launch_bounds__(256) void k_aggz_all(
    AggCtx A, const float* __restrict__ eW, const float* __restrict__ eb, int l)
{
    const int b = blockIdx.x;
    int r = 0;
    while (b >= A.gOff[r + 1]) ++r;
    const int lb = b - A.gOff[r];
    const int wave = threadIdx.x >> 6;
    const int lane = threadIdx.x & 63;
    const int t2 = lane << 1;
    const int lr = l * 7 + r;
    const float* eWr = eW + (size_t)lr * 3 * H;
    const float* ebr = eb + (size_t)lr * H;
    const float w00 = eWr[t2],         w01 = eWr[t2 + 1];
    const float w10 = eWr[H + t2],     w11 = eWr[H + t2 + 1];
    const float w20 = eWr[2 * H + t2], w21 = eWr[2 * H + t2 + 1];
    const float b0 = ebr[t2], b1v = ebr[t2 + 1];

    const int nd = A.nd[r];
    const int d0 = lb * 64 + wave * 16;
    if (d0 >= nd) return;
    const int dend = min(d0 + 16, nd);
    const int* __restrict__ ptr = A.ptr[r];
    const uint4* __restrict__ ce = A.csr_rec[r];
    const unsigned short* __restrict__ hs = A.hsrc[r];
    const unsigned short* __restrict__ hd = A.hdst[r];
    unsigned int* __restrict__ zp = (unsigned int*)A.z[r];

    int p1 = ptr[d0];
    for (int d = d0; d < dend; ++d) {
        const int p0 = p1;
        p1 = ptr[d + 1];
        const unsigned int hdv = ((const unsigned int*)&hd[(size_t)d * H])[lane];
        float acc0 = bf2f(hdv & 0xffffu);
        float acc1 = bf2f(hdv >> 16);
        for (int i = p0; i < p1; i += 4) {
            const int rem = p1 - i;
            const int iB = rem > 1 ? i + 1 : i;
            const int iC = rem > 2 ? i + 2 : i;
            const int iD = rem > 3 ? i + 3 : i;
            const uint4 rA = ce[i], rB = ce[iB], rC = ce[iC], rD = ce[iD];
            const unsigned int hvA = ((const unsigned int*)&hs[(size_t)rA.x * H])[lane];
            const unsigned int hvB = ((const unsigned int*)&hs[(size_t)rB.x * H])[lane];
            const unsigned int hvC = ((const unsigned int*)&hs[(size_t)rC.x * H])[lane];
            const unsigned int hvD = ((const unsigned int*)&hs[(size_t)rD.x * H])[lane];
            {
                const float a0 = bf2f(rA.y & 0xffffu), a1 = bf2f(rA.y >> 16), a2 = bf2f(rA.z & 0xffffu);
                acc0 += fmaxf(bf2f(hvA & 0xffffu) + a0 * w00 + a1 * w10 + a2 * w20 + b0, 0.f);
                acc1 += fmaxf(bf2f(hvA >> 16)     + a0 * w01 + a1 * w11 + a2 * w21 + b1v, 0.f);
            }
            if (rem > 1) {
                const float a0 = bf2f(rB.y & 0xffffu), a1 = bf2f(rB.y >> 16), a2 = bf2f(rB.z & 0xffffu);
                acc0 += fmaxf(bf2f(hvB & 0xffffu) + a0 * w00 + a1 * w10 + a2 * w20 + b0, 0.f);
                acc1 += fmaxf(bf2f(hvB >> 16)     + a0 * w01 + a1 * w11 + a2 * w21 + b1v, 0.f);
            }
            if (rem > 2) {
                const float a0 = bf2f(rC.y & 0xffffu), a1 = bf2f(rC.y >> 16), a2 = bf2f(rC.z & 0xffffu);
                acc0 += fmaxf(bf2f(hvC & 0xffffu) + a0 * w00 + a1 * w10 + a2 * w20 + b0, 0.f);
                acc1 += fmaxf(bf2f(hvC >> 16)     + a0 * w01 + a1 * w11 + a2 * w21 + b1v, 0.f);
            }
            if (rem > 3) {
                const float a0 = bf2f(rD.y & 0xffffu), a1 = bf2f(rD.y >> 16), a2 = bf2f(rD.z & 0xffffu);
                acc0 += fmaxf(bf2f(hvD & 0xffffu) + a0 * w00 + a1 * w10 + a2 * w20 + b0, 0.f);
                acc1 += fmaxf(bf2f(hvD >> 16)     + a0 * w01 + a1 * w11 + a2 * w21 + b1v, 0.f);
            }
        }
        zp[(size_t)d * 64 + (lane ^ ((d & 7) << 2))] =
            (unsigned int)f2bf(acc0) | ((unsigned int)f2bf(acc1) << 16);
    }
}

// ---------------------------------------------------------------------------
// One dispatch per layer: all 3 dst-types' fused MLPs (r17 config: 128-row
// tiles, 512 thr, 64 KB LDS, launch_bounds(512,2), W1+W2 preloaded).
struct MlpCtx {
    const unsigned short* z[3][3];
    int lr[3][3];
    int nrel[3];
    int gend[3];
    int noffH[3];
    int n[3];
};

__global__ __launch_bounds__(512, 2) void k_mlp_all(
    MlpCtx M, const unsigned short* __restrict__ hb,
    unsigned short* __restrict__ hbw, float* __restrict__ fout,
    const unsigned short* __restrict__ wprep,
    const float* __restrict__ b1g, const float* __restrict__ g1g,
    const float* __restrict__ be1g, const float* __restrict__ b2g, int fin)
{
    __shared__ unsigned short smem[2 * 128 * H];   // 64 KB
    unsigned short* zt  = smem;
    unsigned short* a1t = smem + 128 * H;

    const int b = blockIdx.x;
    const int t = (b >= M.gend[0] ? 1 : 0) + (b >= M.gend[1] ? 1 : 0);
    const int lb = b - (t == 0 ? 0 : M.gend[t - 1]);
    const int n = M.n[t];
    const int nrel = M.nrel[t];
    const unsigned short* hbp = hb + (size_t)M.noffH[t];

    const int tid = threadIdx.x;
    const int lane = tid & 63;
    const int wave = tid >> 6;
    const int wr = wave >> 2;
    const int wc = wave & 3;
    const int l15 = lane & 15;
    const int lq  = lane >> 4;
    const int c0 = wc * 32 + l15;

    const int r0 = lb * 128;
    const int rows = min(128, n - r0);
    const bool full = (rows == 128);

    auto stage = [&](const unsigned short* z) {
        const unsigned short* zsrc = z + (size_t)r0 * H;
        if (full) {
#pragma unroll
            for (int it = 0; it < 4; ++it) {
                const int off = (wave * 4 + it) * 512;
                GLDS16(zsrc + off + lane * 8, zt + off);
            }
        } else {
            for (int idx = tid; idx < rows * 16; idx += 512) {
                *(uint4*)&zt[idx * 8] = *(const uint4*)&zsrc[idx * 8];
            }
        }
    };

    const float bn_inv = 0.99999500003749977f;
    const f32x4 Z4 = {0.f, 0.f, 0.f, 0.f};
    f32x4 acc2[4][2];
#pragma unroll
    for (int rb = 0; rb < 4; ++rb)
#pragma unroll
        for (int nf = 0; nf < 2; ++nf) acc2[rb][nf] = Z4;
    float b2s0 = 0.f, b2s1 = 0.f;

    stage(M.z[t][0]);

    for (int rl = 0; rl < nrel; ++rl) {
        const int lr = M.lr[t][rl];
        const unsigned short* wp = wprep + (size_t)lr * 32768;
        short8 w1f[2][4], w2f[2][4];
#pragma unroll
        for (int nf = 0; nf < 2; ++nf)
#pragma unroll
            for (int kc = 0; kc < 4; ++kc) {
                w1f[nf][kc] = *(const short8*)&wp[(c0 + nf * 16) * H + kc * 32 + (lq << 3)];
                w2f[nf][kc] = *(const short8*)&wp[16384 + (c0 + nf * 16) * H + kc * 32 + (lq << 3)];
            }
        const float b1c0 = b1g[lr * H + c0],            b1c1 = b1g[lr * H + c0 + 16];
        const float sc0  = g1g[lr * H + c0] * bn_inv,   sc1  = g1g[lr * H + c0 + 16] * bn_inv;
        const float be0  = be1g[lr * H + c0],           be1v = be1g[lr * H + c0 + 16];
        b2s0 += b2g[lr * H + c0]; b2s1 += b2g[lr * H + c0 + 16];

        __syncthreads();  // A: drains staging -> zt ready

        f32x4 acc1[4][2];
#pragma unroll
        for (int rb = 0; rb < 4; ++rb)
#pragma unroll
            for (int nf = 0; nf < 2; ++nf) acc1[rb][nf] = Z4;
#pragma unroll
        for (int kc = 0; kc < 4; ++kc) {
            const int kb = kc * 32 + (lq << 3);
            short8 af[4];
#pragma unroll
            for (int rb = 0; rb < 4; ++rb) {
                const int row = wr * 64 + rb * 16 + l15;
                af[rb] = *(const short8*)&zt[row * H + (kb ^ ((row & 7) << 3))];
            }
#pragma unroll
            for (int rb = 0; rb < 4; ++rb)
#pragma unroll
                for (int nf = 0; nf < 2; ++nf)
                    acc1[rb][nf] = __builtin_amdgcn_mfma_f32_16x16x32_bf16(
                        af[rb], w1f[nf][kc], acc1[rb][nf], 0, 0, 0);
        }
#pragma unroll
        for (int rb = 0; rb < 4; ++rb)
#pragma unroll
            for (int nf = 0; nf < 2; ++nf) {
                const int col = c0 + nf * 16;
                const float b1c = nf == 0 ? b1c0 : b1c1;
                const float scv = nf == 0 ? sc0 : sc1;
                const float bev = nf == 0 ? be0 : be1v;
#pragma unroll
                for (int rg = 0; rg < 4; ++rg) {
                    const int row = wr * 64 + rb * 16 + (lq << 2) + rg;
                    float v = fmaxf((acc1[rb][nf][rg] + b1c) * scv + bev, 0.f);
                    a1t[row * H + (col ^ ((row & 7) << 3))] = f2bf(v);
                }
            }
        __syncthreads();  // B: a1t ready; zt dead

        if (rl + 1 < nrel) stage(M.z[t][rl + 1]);

#pragma unroll
        for (int kc = 0; kc < 4; ++kc) {
            const int kb = kc * 32 + (lq << 3);
            short8 af[4];
#pragma unroll
            for (int rb = 0; rb < 4; ++rb) {
                const int row = wr * 64 + rb * 16 + l15;
                af[rb] = *(const short8*)&a1t[row * H + (kb ^ ((row & 7) << 3))];
            }
#pragma unroll
            for (int rb = 0; rb < 4; ++rb)
#pragma unroll
                for (int nf = 0; nf < 2; ++nf)
                    acc2[rb][nf] = __builtin_amdgcn_mfma_f32_16x16x32_bf16(
                        af[rb], w2f[nf][kc], acc2[rb][nf], 0, 0, 0);
        }
    }

    if (fin) {
        float* fb = (float*)smem;
        float* foutp = fout + (size_t)M.noffH[t];
        __syncthreads();
#pragma unroll
        for (int rb = 0; rb < 4; ++rb)
#pragma unroll
            for (int nf = 0; nf < 2; ++nf) {
                const int col = c0 + nf * 16;
                const float b2s = nf == 0 ? b2s0 : b2s1;
#pragma unroll
                for (int rg = 0; rg < 4; ++rg) {
                    const int row = wr * 64 + rb * 16 + (lq << 2) + rg;
                    if (row < rows) {
                        const size_t o = (size_t)(r0 + row) * H + col;
                        fb[row * H + col] = eluf(acc2[rb][nf][rg] + b2s
                                                 + bf2f((unsigned int)hbp[o]));
                    }
                }
            }
        __syncthreads();
        float4* d4 = (float4*)&foutp[(size_t)r0 * H];
        const float4* s4 = (const float4*)fb;
        for (int idx = tid; idx < rows * 32; idx += 512) d4[idx] = s4[idx];
    } else {
        unsigned short* hbwp = hbw + (size_t)M.noffH[t];
        __syncthreads();
#pragma unroll
        for (int rb = 0; rb < 4; ++rb)
#pragma unroll
            for (int nf = 0; nf < 2; ++nf) {
                const int col = c0 + nf * 16;
                const float b2s = nf == 0 ? b2s0 : b2s1;
#pragma unroll
                for (int rg = 0; rg < 4; ++rg) {
                    const int row = wr * 64 + rb * 16 + (lq << 2) + rg;
                    if (row < rows) {
                        const size_t o = (size_t)(r0 + row) * H + col;
                        a1t[row * H + col] = f2bf(eluf(acc2[rb][nf][rg] + b2s
                                                       + bf2f((unsigned int)hbp[o])));
                    }
                }
            }
        __syncthreads();
        uint2* d = (uint2*)&hbwp[(size_t)r0 * H];
        const uint2* s2 = (const uint2*)a1t;
        for (int idx = tid; idx < rows * 32; idx += 512) d[idx] = s2[idx];
    }
}

static inline int imin(int a, int b) { return a < b ? a : b; }
static inline int imax(int a, int b) { return a > b ? a : b; }
static inline size_t alignup(size_t x) { return (x + 255) & ~(size_t)255; }

extern "C" void kernel_launch(void* const* d_in, const int* in_sizes, int n_in,
                              void* d_out, int out_size, void* d_ws, size_t ws_size,
                              hipStream_t stream) {
    const float* xin[3] = {(const float*)d_in[0], (const float*)d_in[1], (const float*)d_in[2]};
    const int* src[7]; const int* dst[7]; const float* ea[7]; int E[7];
    for (int r = 0; r < 7; ++r) {
        src[r] = (const int*)d_in[3 + 3 * r];
        dst[r] = (const int*)d_in[4 + 3 * r];
        ea[r]  = (const float*)d_in[5 + 3 * r];
        E[r]   = in_sizes[3 + 3 * r];
    }
    const float* linW[3] = {(const float*)d_in[24], (const float*)d_in[26], (const float*)d_in[28]};
    const float* linb[3] = {(const float*)d_in[25], (const float*)d_in[27], (const float*)d_in[29]};
    const float* eW  = (const float*)d_in[30];
    const float* ebp = (const float*)d_in[31];
    const float* W1  = (const float*)d_in[32];
    const float* b1  = (const float*)d_in[33];
    const float* g1  = (const float*)d_in[34];
    const float* be1 = (const float*)d_in[35];
    const float* W2  = (const float*)d_in[36];
    const float* b2  = (const float*)d_in[37];

    const int NSn[3]  = {in_sizes[0] / 64, in_sizes[1] / 64, in_sizes[2] / 64};
    const int NTOT = NSn[0] + NSn[1] + NSn[2];
    const int noff[3] = {0, NSn[0], NSn[0] + NSn[1]};

    float* fout = (float*)d_out;

    // prefixes
    int bOff[8]; bOff[0] = 0;
    for (int r = 0; r < 7; ++r) bOff[r + 1] = bOff[r] + (NSn[DST_T_[r]] + 255) / 256;
    int gOff[8]; gOff[0] = 0;
    for (int r = 0; r < 7; ++r) gOff[r + 1] = gOff[r] + (NSn[DST_T_[r]] + 63) / 64;

    // workspace carve-up
    char* wsb = (char*)d_ws;
    size_t off = 0;
    unsigned short* hb = (unsigned short*)(wsb + off); off = alignup(off + (size_t)NTOT * H * 2);
    unsigned short* zb[7];
    for (int r = 0; r < 7; ++r) {
        int nd = NSn[DST_T_[r]];
        zb[r] = (unsigned short*)(wsb + off); off = alignup(off + (size_t)nd * H * 2);
    }
    unsigned short* wprep = (unsigned short*)(wsb + off); off = alignup(off + (size_t)21 * 32768 * 2);
    unsigned short* wlin  = (unsigned short*)(wsb + off); off = alignup(off + (size_t)3 * 8192 * 2);
    int* deg    = (int*)(wsb + off); off = alignup(off + (size_t)bOff[7] * 256 * 4);
    int* cursor = (int*)(wsb + off); off = alignup(off + (size_t)bOff[7] * 256 * 4);
    int* bsum   = (int*)(wsb + off); off = alignup(off + (size_t)bOff[7] * 4 + 256);
    int* ptrs[7]; uint4* recs[7];
    for (int r = 0; r < 7; ++r) {
        int nd = NSn[DST_T_[r]];
        ptrs[r] = (int*)(wsb + off); off = alignup(off + (size_t)(nd + 1) * 4);
    }
    for (int r = 0; r < 7; ++r) {
        recs[r] = (uint4*)(wsb + off); off = alignup(off + (size_t)E[r] * 16);
    }

    // ---- preamble: hist + weight prep ----
    PreCtx P;
    for (int r = 0; r < 7; ++r) { P.dst[r] = dst[r]; P.E[r] = E[r]; }
    P.deg = deg;
    for (int r = 0; r < 8; ++r) P.bOff[r] = bOff[r];
    P.hOff[0] = 0;
    for (int r = 0; r < 7; ++r)
        P.hOff[r + 1] = P.hOff[r] + imax(1, (E[r] + 1023) / 1024);
    P.W1 = W1; P.W2 = W2; P.wp = wprep; P.wlin = wlin;
    for (int t = 0; t < 3; ++t) P.linW[t] = linW[t];
    P.gEnd = P.hOff[7] + 256;

    hipMemsetAsync(deg, 0, (size_t)bOff[7] * 256 * 4, stream);
    k_pre<<<P.gEnd, 256, 0, stream>>>(P);

    // ---- MFMA input embedding ----
    InCtx I;
    int ig = 0;
    for (int t = 0; t < 3; ++t) {
        I.x[t] = xin[t]; I.linb[t] = linb[t];
        I.hb[t] = hb + (size_t)noff[t] * H; I.n[t] = NSn[t];
        ig += (NSn[t] + 127) / 128;
        I.gend[t] = ig;
    }
    k_input_mfma<<<ig, 512, 0, stream>>>(I, wlin);

    // ---- CSR scans + scatter ----
    CsrCtx C;
    for (int r = 0; r < 7; ++r) {
        C.src[r] = src[r]; C.dst[r] = dst[r]; C.ea[r] = ea[r];
        C.csr_rec[r] = recs[r]; C.ptr[r] = ptrs[r];
        C.nd[r] = NSn[DST_T_[r]];
        C.E[r] = E[r];
    }
    C.deg = deg; C.cursor = cursor; C.bsum = bsum;
    for (int r = 0; r < 8; ++r) C.bOff[r] = bOff[r];
    C.sOff[0] = 0;
    for (int r = 0; r < 7; ++r)
        C.sOff[r + 1] = C.sOff[r] + imax(1, (E[r] + 1023) / 1024);

    k_scan_partial_all<<<bOff[7], 256, 0, stream>>>(C);
    k_scan_mid_all<<<7, 512, 0, stream>>>(C);
    k_scan_final_all<<<bOff[7], 256, 0, stream>>>(C);
    k_scatter_all<<<C.sOff[7], 256, 0, stream>>>(C);

    // ---- agg context ----
    AggCtx A;
    for (int r = 0; r < 7; ++r) {
        A.ptr[r] = ptrs[r]; A.csr_rec[r] = recs[r];
        A.hsrc[r] = hb + (size_t)noff[SRC_T_[r]] * H;
        A.hdst[r] = hb + (size_t)noff[DST_T_[r]] * H;
        A.z[r] = zb[r];
        A.nd[r] = NSn[DST_T_[r]];
    }
    for (int r = 0; r < 8; ++r) A.gOff[r] = gOff[r];

    // ---- mlp context (128-row tiles) ----
    static const int RELS[3][3] = {{0, 2, 0}, {1, 3, 5}, {4, 6, 0}};
    static const int NRELS[3] = {2, 3, 2};
    MlpCtx M;
    int gend = 0;
    for (int t = 0; t < 3; ++t) {
        M.nrel[t] = NRELS[t];
        M.noffH[t] = noff[t] * H;
        M.n[t] = NSn[t];
        gend += (NSn[t] + 127) / 128;
        M.gend[t] = gend;
        for (int k = 0; k < 3; ++k) M.z[t][k] = zb[RELS[t][k]];
    }

    // ---- layers ----
    for (int l = 0; l < 3; ++l) {
        const int fin = (l == 2) ? 1 : 0;
        k_aggz_all<<<gOff[7], 256, 0, stream>>>(A, eW, ebp, l);
        for (int t = 0; t < 3; ++t)
            for (int k = 0; k < 3; ++k) M.lr[t][k] = l * 7 + RELS[t][k];
        k_mlp_all<<<M.gend[2], 512, 0, stream>>>(
            M, hb, hb, fout, wprep, b1, g1, be1, b2, fin);
    }
}

// Round 20
// 754.380 us; speedup vs baseline: 1.0391x; 1.0387x over previous
//
#include <hip/hip_runtime.h>
#include <math.h>

#define H 128

typedef __attribute__((ext_vector_type(8))) short short8;
typedef __attribute__((ext_vector_type(4))) float f32x4;

static const int SRC_T_[7] = {0, 0, 1, 1, 1, 2, 2};
static const int DST_T_[7] = {0, 1, 0, 1, 2, 1, 2};

__device__ __forceinline__ float eluf(float x) {
    return x > 0.f ? x : (__expf(x) - 1.f);
}
__device__ __forceinline__ unsigned short f2bf(float x) {  // RNE f32->bf16
    union { float f; unsigned int u; } v; v.f = x;
    unsigned int r = v.u + 0x7fffu + ((v.u >> 16) & 1u);
    return (unsigned short)(r >> 16);
}
__device__ __forceinline__ float bf2f(unsigned int u) {
    union { unsigned int u; float f; } v; v.u = u << 16;
    return v.f;
}

// async global->LDS, 16 bytes per lane; lds base wave-uniform, gsrc per-lane
#define GLDS16(gp, lp) __builtin_amdgcn_global_load_lds( \
    (const __attribute__((address_space(1))) void*)(gp), \
    (__attribute__((address_space(3))) void*)(lp), 16, 0, 0)

// ---------------------------------------------------------------------------
// k_pre: [hist (per-rel block ranges) | weight prep (mlp + input)] — no LDS.
struct PreCtx {
    const int* dst[7];
    int* deg;
    int E[7], bOff[8], hOff[8];
    const float* W1; const float* W2; const float* linW[3];
    unsigned short* wp; unsigned short* wlin;
    int gEnd;
};

__global__ __launch_bounds__(256) void k_pre(PreCtx P)
{
    const int b = blockIdx.x;
    const int tid = threadIdx.x;

    if (b < P.hOff[7]) {                  // ---- histogram ----
        int r = 0;
        while (b >= P.hOff[r + 1]) ++r;
        const int lb = b - P.hOff[r];
        const int nb = P.hOff[r + 1] - P.hOff[r];
        const int* dst = P.dst[r];
        int* degr = P.deg + (P.bOff[r] << 8);
        for (int e = lb * 256 + tid; e < P.E[r]; e += nb * 256)
            atomicAdd(&degr[dst[e]], 1);
        return;
    }
    {                                     // ---- weight prep ----
        const int lb = b - P.hOff[7];
        const int gw = P.gEnd - P.hOff[7];
        for (int i = lb * 256 + tid; i < 21 * 16384; i += gw * 256) {
            int lr = i >> 14, rem = i & 16383;
            int c = rem >> 7, k = rem & 127;
            P.wp[(size_t)(lr * 2 + 0) * 16384 + rem] = f2bf(P.W1[(size_t)lr * 16384 + k * H + c]);
            P.wp[(size_t)(lr * 2 + 1) * 16384 + rem] = f2bf(P.W2[(size_t)lr * 16384 + k * H + c]);
        }
        // input weights: linW[t] [64k][128c] f32 -> wlin [t][128c][64k] bf16
        for (int i = lb * 256 + tid; i < 3 * 8192; i += gw * 256) {
            int t = i >> 13, rem = i & 8191;
            int c = rem >> 6, k = rem & 63;
            P.wlin[t * 8192 + c * 64 + k] = f2bf(P.linW[t][k * H + c]);
        }
    }
}

// ---------------------------------------------------------------------------
// MFMA input embedding: hb[t] = bf16(elu(x @ W + b)); x:[n,64] f32.
struct InCtx {
    const float* x[3]; const float* linb[3];
    unsigned short* hb[3]; int n[3];
    int gend[3];
};

__global__ __launch_bounds__(512, 2) void k_input_mfma(
    InCtx I, const unsigned short* __restrict__ wlin)
{
    __shared__ unsigned short xb[128 * 64];   // 16 KB, XOR-swizzled
    __shared__ unsigned short ob[128 * H];    // 32 KB

    const int b = blockIdx.x;
    const int t = (b >= I.gend[0] ? 1 : 0) + (b >= I.gend[1] ? 1 : 0);
    const int lb = b - (t == 0 ? 0 : I.gend[t - 1]);
    const int n = I.n[t];
    const int tid = threadIdx.x;
    const int lane = tid & 63;
    const int wave = tid >> 6;
    const int wr = wave >> 2;
    const int wc = wave & 3;
    const int l15 = lane & 15;
    const int lq  = lane >> 4;
    const int c0 = wc * 32 + l15;
    const int r0 = lb * 128;
    const int rows = min(128, n - r0);
    const float* x = I.x[t];

    for (int idx = tid; idx < 128 * 16; idx += 512) {
        const int row = idx >> 4, cg = (idx & 15) << 2;
        uint2 p;
        if (row < rows) {
            f32x4 v = *(const f32x4*)&x[(size_t)(r0 + row) * 64 + cg];
            p.x = (unsigned int)f2bf(v.x) | ((unsigned int)f2bf(v.y) << 16);
            p.y = (unsigned int)f2bf(v.z) | ((unsigned int)f2bf(v.w) << 16);
        } else { p.x = 0; p.y = 0; }
        *(uint2*)&xb[row * 64 + (cg ^ ((row & 7) << 3))] = p;
    }
    const unsigned short* wt = wlin + (size_t)t * 8192;
    short8 wf[2][2];
#pragma unroll
    for (int nf = 0; nf < 2; ++nf)
#pragma unroll
        for (int kc = 0; kc < 2; ++kc)
            wf[nf][kc] = *(const short8*)&wt[(c0 + nf * 16) * 64 + kc * 32 + (lq << 3)];
    const float bc0 = I.linb[t][c0], bc1 = I.linb[t][c0 + 16];
    __syncthreads();

    const f32x4 Z4 = {0.f, 0.f, 0.f, 0.f};
    f32x4 acc[4][2];
#pragma unroll
    for (int rb = 0; rb < 4; ++rb)
#pragma unroll
        for (int nf = 0; nf < 2; ++nf) acc[rb][nf] = Z4;
#pragma unroll
    for (int kc = 0; kc < 2; ++kc) {
        const int kb = kc * 32 + (lq << 3);
        short8 af[4];
#pragma unroll
        for (int rb = 0; rb < 4; ++rb) {
            const int row = wr * 64 + rb * 16 + l15;
            af[rb] = *(const short8*)&xb[row * 64 + (kb ^ ((row & 7) << 3))];
        }
#pragma unroll
        for (int rb = 0; rb < 4; ++rb)
#pragma unroll
            for (int nf = 0; nf < 2; ++nf)
                acc[rb][nf] = __builtin_amdgcn_mfma_f32_16x16x32_bf16(
                    af[rb], wf[nf][kc], acc[rb][nf], 0, 0, 0);
    }
#pragma unroll
    for (int rb = 0; rb < 4; ++rb)
#pragma unroll
        for (int nf = 0; nf < 2; ++nf) {
            const int col = c0 + nf * 16;
            const float bc = nf == 0 ? bc0 : bc1;
#pragma unroll
            for (int rg = 0; rg < 4; ++rg) {
                const int row = wr * 64 + rb * 16 + (lq << 2) + rg;
                ob[row * H + col] = f2bf(eluf(acc[rb][nf][rg] + bc));
            }
        }
    __syncthreads();
    uint2* d = (uint2*)&I.hb[t][(size_t)r0 * H];
    const uint2* s2 = (const uint2*)ob;
    for (int idx = tid; idx < rows * 32; idx += 512) d[idx] = s2[idx];
}

// --------------------------- batched CSR build ------------------------------
struct CsrCtx {
    const int* src[7]; const int* dst[7]; const float* ea[7];
    int* csr_src[7]; uint2* csr_ea[7]; int* ptr[7];
    int* deg; int* cursor; int* bsum;
    int eOff[8];
    int bOff[8];
    int nd[7];
};

__global__ __launch_bounds__(256) void k_scan_partial_all(CsrCtx C)
{
    __shared__ int s[256];
    const int b = blockIdx.x;
    int r = 0;
    while (b >= C.bOff[r + 1]) ++r;
    const int lb = b - C.bOff[r];
    const int tid = threadIdx.x;
    const int idx = lb * 256 + tid;
    s[tid] = idx < C.nd[r] ? C.deg[(C.bOff[r] << 8) + idx] : 0;
    __syncthreads();
    for (int off = 128; off > 0; off >>= 1) {
        if (tid < off) s[tid] += s[tid + off];
        __syncthreads();
    }
    if (tid == 0) C.bsum[b] = s[0];
}

__global__ __launch_bounds__(512) void k_scan_mid_all(CsrCtx C)
{
    __shared__ int s[512];
    const int r = blockIdx.x;
    const int nb = C.bOff[r + 1] - C.bOff[r];
    const int tid = threadIdx.x;
    const int v = tid < nb ? C.bsum[C.bOff[r] + tid] : 0;
    s[tid] = v;
    __syncthreads();
    for (int off = 1; off < 512; off <<= 1) {
        int t = (tid >= off) ? s[tid - off] : 0;
        __syncthreads();
        s[tid] += t;
        __syncthreads();
    }
    if (tid < nb) C.bsum[C.bOff[r] + tid] = s[tid] - v;
    if (tid == nb - 1) C.ptr[r][C.nd[r]] = s[tid];
}

__global__ __launch_bounds__(256) void k_scan_final_all(CsrCtx C)
{
    __shared__ int s[256];
    const int b = blockIdx.x;
    int r = 0;
    while (b >= C.bOff[r + 1]) ++r;
    const int lb = b - C.bOff[r];
    const int tid = threadIdx.x;
    const int idx = lb * 256 + tid;
    const int v = idx < C.nd[r] ? C.deg[(C.bOff[r] << 8) + idx] : 0;
    s[tid] = v;
    __syncthreads();
    for (int off = 1; off < 256; off <<= 1) {
        int t = (tid >= off) ? s[tid - off] : 0;
        __syncthreads();
        s[tid] += t;
        __syncthreads();
    }
    if (idx < C.nd[r]) {
        const int excl = s[tid] - v + C.bsum[b];
        C.ptr[r][idx] = excl;
        C.cursor[(C.bOff[r] << 8) + idx] = excl;
    }
}

__global__ __launch_bounds__(256) void k_scatter_all(CsrCtx C, int Etot)
{
    for (int e = blockIdx.x * 256 + threadIdx.x; e < Etot; e += gridDim.x * 256) {
        int r = 0;
        while (e >= C.eOff[r + 1]) ++r;
        const int le = e - C.eOff[r];
        const int d = C.dst[r][le];
        const int pos = atomicAdd(&C.cursor[(C.bOff[r] << 8) + d], 1);
        C.csr_src[r][pos] = C.src[r][le];
        const float* eap = C.ea[r] + (size_t)3 * le;
        uint2 p;
        p.x = (unsigned int)f2bf(eap[0]) | ((unsigned int)f2bf(eap[1]) << 16);
        p.y = (unsigned int)f2bf(eap[2]);
        C.csr_ea[r][pos] = p;
    }
}

// ---------------------------------------------------------------------------
// Batched gather-aggregate: per-relation block ranges; 4 waves/block;
// wave = 16 consecutive nodes, full wave per node (2 cols/lane).
// 2-stage software pipeline; z written PRE-SWIZZLED (uint idx ^ (d&7)<<2).
struct AggCtx {
    const int* ptr[7]; const int* csr_src[7]; const uint2* csr_ea[7];
    const unsigned short* hsrc[7]; const unsigned short* hdst[7];
    unsigned short* z[7];
    int gOff[8];
    int nd[7];
};

__global__ __launch_bounds__(256) void k_aggz_all(
    AggCtx A, const float* __restrict__ eW, const float* __restrict__ eb, int l)
{
    const int b = blockIdx.x;
    int r = 0;
    while (b >= A.gOff[r + 1]) ++r;
    const int lb = b - A.gOff[r];
    const int wave = threadIdx.x >> 6;
    const int lane = threadIdx.x & 63;
    const int t2 = lane << 1;
    const int lr = l * 7 + r;
    const float* eWr = eW + (size_t)lr * 3 * H;
    const float* ebr = eb + (size_t)lr * H;
    const float w00 = eWr[t2],         w01 = eWr[t2 + 1];
    const float w10 = eWr[H + t2],     w11 = eWr[H + t2 + 1];
    const float w20 = eWr[2 * H + t2], w21 = eWr[2 * H + t2 + 1];
    const float b0 = ebr[t2], b1v = ebr[t2 + 1];

    const int nd = A.nd[r];
    const int d0 = lb * 64 + wave * 16;
    if (d0 >= nd) return;
    const int dend = min(d0 + 16, nd);
    const int* __restrict__ ptr = A.ptr[r];
    const int* __restrict__ cs = A.csr_src[r];
    const uint2* __restrict__ ce = A.csr_ea[r];
    const unsigned short* __restrict__ hs = A.hsrc[r];
    const unsigned short* __restrict__ hd = A.hdst[r];
    unsigned int* __restrict__ zp = (unsigned int*)A.z[r];

    int p1 = ptr[d0];
    for (int d = d0; d < dend; ++d) {
        const int p0v = p1;
        p1 = ptr[d + 1];
        const unsigned int hdv = ((const unsigned int*)&hd[(size_t)d * H])[lane];
        float acc0 = bf2f(hdv & 0xffffu);
        float acc1 = bf2f(hdv >> 16);
        int i = p0v;
        if (i + 1 < p1) {
            int s0 = cs[i], s1 = cs[i + 1];
            uint2 eC0 = ce[i], eC1 = ce[i + 1];
            unsigned int hvC0 = ((const unsigned int*)&hs[(size_t)s0 * H])[lane];
            unsigned int hvC1 = ((const unsigned int*)&hs[(size_t)s1 * H])[lane];
            for (;;) {
                const int jn = i + 2;
                const bool more = (jn + 1 < p1);
                uint2 eN0, eN1; unsigned int hvN0 = 0, hvN1 = 0;
                if (more) {
                    const int sN0 = cs[jn], sN1 = cs[jn + 1];
                    eN0 = ce[jn]; eN1 = ce[jn + 1];
                    hvN0 = ((const unsigned int*)&hs[(size_t)sN0 * H])[lane];
                    hvN1 = ((const unsigned int*)&hs[(size_t)sN1 * H])[lane];
                }
                const float a00 = bf2f(eC0.x & 0xffffu), a01 = bf2f(eC0.x >> 16), a02 = bf2f(eC0.y & 0xffffu);
                const float a10 = bf2f(eC1.x & 0xffffu), a11 = bf2f(eC1.x >> 16), a12 = bf2f(eC1.y & 0xffffu);
                acc0 += fmaxf(bf2f(hvC0 & 0xffffu) + a00 * w00 + a01 * w10 + a02 * w20 + b0, 0.f)
                      + fmaxf(bf2f(hvC1 & 0xffffu) + a10 * w00 + a11 * w10 + a12 * w20 + b0, 0.f);
                acc1 += fmaxf(bf2f(hvC0 >> 16) + a00 * w01 + a01 * w11 + a02 * w21 + b1v, 0.f)
                      + fmaxf(bf2f(hvC1 >> 16) + a10 * w01 + a11 * w11 + a12 * w21 + b1v, 0.f);
                i = jn;
                if (!more) break;
                eC0 = eN0; eC1 = eN1; hvC0 = hvN0; hvC1 = hvN1;
            }
        }
        if (i < p1) {
            const int s = cs[i];
            const uint2 ep = ce[i];
            const float a0 = bf2f(ep.x & 0xffffu);
            const float a1 = bf2f(ep.x >> 16);
            const float a2 = bf2f(ep.y & 0xffffu);
            const unsigned int hv = ((const unsigned int*)&hs[(size_t)s * H])[lane];
            acc0 += fmaxf(bf2f(hv & 0xffffu) + a0 * w00 + a1 * w10 + a2 * w20 + b0, 0.f);
            acc1 += fmaxf(bf2f(hv >> 16)     + a0 * w01 + a1 * w11 + a2 * w21 + b1v, 0.f);
        }
        zp[(size_t)d * 64 + (lane ^ ((d & 7) << 2))] =
            (unsigned int)f2bf(acc0) | ((unsigned int)f2bf(acc1) << 16);
    }
}

// ---------------------------------------------------------------------------
// One dispatch per layer: all 3 dst-types' fused MLPs.
// z pre-swizzled in global; staged via global_load_lds; next relation's
// staging issued after the a1t barrier. W1+W2 fragments preloaded so both
// GEMM loops are pure LDS+MFMA. launch_bounds(512,2): 2 blocks/CU (LDS cap),
// 128 VGPR budget -> no spills.
struct MlpCtx {
    const unsigned short* z[3][3];
    int lr[3][3];
    int nrel[3];
    int gend[3];
    int noffH[3];
    int n[3];
};

__global__ __launch_bounds__(512, 2) void k_mlp_all(
    MlpCtx M, const unsigned short* __restrict__ hb,
    unsigned short* __restrict__ hbw, float* __restrict__ fout,
    const unsigned short* __restrict__ wprep,
    const float* __restrict__ b1g, const float* __restrict__ g1g,
    const float* __restrict__ be1g, const float* __restrict__ b2g, int fin)
{
    __shared__ unsigned short smem[2 * 128 * H];   // 64 KB
    unsigned short* zt  = smem;
    unsigned short* a1t = smem + 128 * H;

    const int b = blockIdx.x;
    const int t = (b >= M.gend[0] ? 1 : 0) + (b >= M.gend[1] ? 1 : 0);
    const int lb = b - (t == 0 ? 0 : M.gend[t - 1]);
    const int n = M.n[t];
    const int nrel = M.nrel[t];
    const unsigned short* hbp = hb + (size_t)M.noffH[t];

    const int tid = threadIdx.x;
    const int lane = tid & 63;
    const int wave = tid >> 6;
    const int wr = wave >> 2;
    const int wc = wave & 3;
    const int l15 = lane & 15;
    const int lq  = lane >> 4;
    const int c0 = wc * 32 + l15;

    const int r0 = lb * 128;
    const int rows = min(128, n - r0);
    const bool full = (rows == 128);

    auto stage = [&](const unsigned short* z) {
        const unsigned short* zsrc = z + (size_t)r0 * H;
        if (full) {
#pragma unroll
            for (int it = 0; it < 4; ++it) {
                const int off = (wave * 4 + it) * 512;
                GLDS16(zsrc + off + lane * 8, zt + off);
            }
        } else {
            for (int idx = tid; idx < rows * 16; idx += 512) {
                *(uint4*)&zt[idx * 8] = *(const uint4*)&zsrc[idx * 8];
            }
        }
    };

    const float bn_inv = 0.99999500003749977f;
    const f32x4 Z4 = {0.f, 0.f, 0.f, 0.f};
    f32x4 acc2[4][2];
#pragma unroll
    for (int rb = 0; rb < 4; ++rb)
#pragma unroll
        for (int nf = 0; nf < 2; ++nf) acc2[rb][nf] = Z4;
    float b2s0 = 0.f, b2s1 = 0.f;

    stage(M.z[t][0]);

    for (int rl = 0; rl < nrel; ++rl) {
        const int lr = M.lr[t][rl];
        const unsigned short* wp = wprep + (size_t)lr * 32768;
        short8 w1f[2][4], w2f[2][4];
#pragma unroll
        for (int nf = 0; nf < 2; ++nf)
#pragma unroll
            for (int kc = 0; kc < 4; ++kc) {
                w1f[nf][kc] = *(const short8*)&wp[(c0 + nf * 16) * H + kc * 32 + (lq << 3)];
                w2f[nf][kc] = *(const short8*)&wp[16384 + (c0 + nf * 16) * H + kc * 32 + (lq << 3)];
            }
        const float b1c0 = b1g[lr * H + c0],            b1c1 = b1g[lr * H + c0 + 16];
        const float sc0  = g1g[lr * H + c0] * bn_inv,   sc1  = g1g[lr * H + c0 + 16] * bn_inv;
        const float be0  = be1g[lr * H + c0],           be1v = be1g[lr * H + c0 + 16];
        b2s0 += b2g[lr * H + c0]; b2s1 += b2g[lr * H + c0 + 16];

        __syncthreads();  // A: drains staging -> zt ready

        f32x4 acc1[4][2];
#pragma unroll
        for (int rb = 0; rb < 4; ++rb)
#pragma unroll
            for (int nf = 0; nf < 2; ++nf) acc1[rb][nf] = Z4;
#pragma unroll
        for (int kc = 0; kc < 4; ++kc) {
            const int kb = kc * 32 + (lq << 3);
            short8 af[4];
#pragma unroll
            for (int rb = 0; rb < 4; ++rb) {
                const int row = wr * 64 + rb * 16 + l15;
                af[rb] = *(const short8*)&zt[row * H + (kb ^ ((row & 7) << 3))];
            }
#pragma unroll
            for (int rb = 0; rb < 4; ++rb)
#pragma unroll
                for (int nf = 0; nf < 2; ++nf)
                    acc1[rb][nf] = __builtin_amdgcn_mfma_f32_16x16x32_bf16(
                        af[rb], w1f[nf][kc], acc1[rb][nf], 0, 0, 0);
        }
#pragma unroll
        for (int rb = 0; rb < 4; ++rb)
#pragma unroll
            for (int nf = 0; nf < 2; ++nf) {
                const int col = c0 + nf * 16;
                const float b1c = nf == 0 ? b1c0 : b1c1;
                const float scv = nf == 0 ? sc0 : sc1;
                const float bev = nf == 0 ? be0 : be1v;
#pragma unroll
                for (int rg = 0; rg < 4; ++rg) {
                    const int row = wr * 64 + rb * 16 + (lq << 2) + rg;
                    float v = fmaxf((acc1[rb][nf][rg] + b1c) * scv + bev, 0.f);
                    a1t[row * H + (col ^ ((row & 7) << 3))] = f2bf(v);
                }
            }
        __syncthreads();  // B: a1t ready; zt dead

        if (rl + 1 < nrel) stage(M.z[t][rl + 1]);

#pragma unroll
        for (int kc = 0; kc < 4; ++kc) {
            const int kb = kc * 32 + (lq << 3);
            short8 af[4];
#pragma unroll
            for (int rb = 0; rb < 4; ++rb) {
                const int row = wr * 64 + rb * 16 + l15;
                af[rb] = *(const short8*)&a1t[row * H + (kb ^ ((row & 7) << 3))];
            }
#pragma unroll
            for (int rb = 0; rb < 4; ++rb)
#pragma unroll
                for (int nf = 0; nf < 2; ++nf)
                    acc2[rb][nf] = __builtin_amdgcn_mfma_f32_16x16x32_bf16(
                        af[rb], w2f[nf][kc], acc2[rb][nf], 0, 0, 0);
        }
    }

    if (fin) {
        float* fb = (float*)smem;
        float* foutp = fout + (size_t)M.noffH[t];
        __syncthreads();
#pragma unroll
        for (int rb = 0; rb < 4; ++rb)
#pragma unroll
            for (int nf = 0; nf < 2; ++nf) {
                const int col = c0 + nf * 16;
                const float b2s = nf == 0 ? b2s0 : b2s1;
#pragma unroll
                for (int rg = 0; rg < 4; ++rg) {
                    const int row = wr * 64 + rb * 16 + (lq << 2) + rg;
                    if (row < rows) {
                        const size_t o = (size_t)(r0 + row) * H + col;
                        fb[row * H + col] = eluf(acc2[rb][nf][rg] + b2s
                                                 + bf2f((unsigned int)hbp[o]));
                    }
                }
            }
        __syncthreads();
        float4* d4 = (float4*)&foutp[(size_t)r0 * H];
        const float4* s4 = (const float4*)fb;
        for (int idx = tid; idx < rows * 32; idx += 512) d4[idx] = s4[idx];
    } else {
        unsigned short* hbwp = hbw + (size_t)M.noffH[t];
        __syncthreads();
#pragma unroll
        for (int rb = 0; rb < 4; ++rb)
#pragma unroll
            for (int nf = 0; nf < 2; ++nf) {
                const int col = c0 + nf * 16;
                const float b2s = nf == 0 ? b2s0 : b2s1;
#pragma unroll
                for (int rg = 0; rg < 4; ++rg) {
                    const int row = wr * 64 + rb * 16 + (lq << 2) + rg;
                    if (row < rows) {
                        const size_t o = (size_t)(r0 + row) * H + col;
                        a1t[row * H + col] = f2bf(eluf(acc2[rb][nf][rg] + b2s
                                                       + bf2f((unsigned int)hbp[o])));
                    }
                }
            }
        __syncthreads();
        uint2* d = (uint2*)&hbwp[(size_t)r0 * H];
        const uint2* s2 = (const uint2*)a1t;
        for (int idx = tid; idx < rows * 32; idx += 512) d[idx] = s2[idx];
    }
}

static inline int imin(int a, int b) { return a < b ? a : b; }
static inline int imax(int a, int b) { return a > b ? a : b; }
static inline size_t alignup(size_t x) { return (x + 255) & ~(size_t)255; }

extern "C" void kernel_launch(void* const* d_in, const int* in_sizes, int n_in,
                              void* d_out, int out_size, void* d_ws, size_t ws_size,
                              hipStream_t stream) {
    const float* xin[3] = {(const float*)d_in[0], (const float*)d_in[1], (const float*)d_in[2]};
    const int* src[7]; const int* dst[7]; const float* ea[7]; int E[7];
    for (int r = 0; r < 7; ++r) {
        src[r] = (const int*)d_in[3 + 3 * r];
        dst[r] = (const int*)d_in[4 + 3 * r];
        ea[r]  = (const float*)d_in[5 + 3 * r];
        E[r]   = in_sizes[3 + 3 * r];
    }
    const float* linW[3] = {(const float*)d_in[24], (const float*)d_in[26], (const float*)d_in[28]};
    const float* linb[3] = {(const float*)d_in[25], (const float*)d_in[27], (const float*)d_in[29]};
    const float* eW  = (const float*)d_in[30];
    const float* ebp = (const float*)d_in[31];
    const float* W1  = (const float*)d_in[32];
    const float* b1  = (const float*)d_in[33];
    const float* g1  = (const float*)d_in[34];
    const float* be1 = (const float*)d_in[35];
    const float* W2  = (const float*)d_in[36];
    const float* b2  = (const float*)d_in[37];

    const int NSn[3]  = {in_sizes[0] / 64, in_sizes[1] / 64, in_sizes[2] / 64};
    const int NTOT = NSn[0] + NSn[1] + NSn[2];
    const int noff[3] = {0, NSn[0], NSn[0] + NSn[1]};

    float* fout = (float*)d_out;

    // prefixes
    int eOff[8]; eOff[0] = 0;
    for (int r = 0; r < 7; ++r) eOff[r + 1] = eOff[r] + E[r];
    const int Etot = eOff[7];
    int bOff[8]; bOff[0] = 0;
    for (int r = 0; r < 7; ++r) bOff[r + 1] = bOff[r] + (NSn[DST_T_[r]] + 255) / 256;
    int gOff[8]; gOff[0] = 0;
    for (int r = 0; r < 7; ++r) gOff[r + 1] = gOff[r] + (NSn[DST_T_[r]] + 63) / 64;

    // workspace carve-up
    char* wsb = (char*)d_ws;
    size_t off = 0;
    unsigned short* hb = (unsigned short*)(wsb + off); off = alignup(off + (size_t)NTOT * H * 2);
    unsigned short* zb[7];
    for (int r = 0; r < 7; ++r) {
        int nd = NSn[DST_T_[r]];
        zb[r] = (unsigned short*)(wsb + off); off = alignup(off + (size_t)nd * H * 2);
    }
    unsigned short* wprep = (unsigned short*)(wsb + off); off = alignup(off + (size_t)21 * 32768 * 2);
    unsigned short* wlin  = (unsigned short*)(wsb + off); off = alignup(off + (size_t)3 * 8192 * 2);
    int* deg    = (int*)(wsb + off); off = alignup(off + (size_t)bOff[7] * 256 * 4);
    int* cursor = (int*)(wsb + off); off = alignup(off + (size_t)bOff[7] * 256 * 4);
    int* bsum   = (int*)(wsb + off); off = alignup(off + (size_t)bOff[7] * 4 + 256);
    int* ptrs[7]; int* csrs[7]; uint2* ceas[7];
    for (int r = 0; r < 7; ++r) {
        int nd = NSn[DST_T_[r]];
        ptrs[r] = (int*)(wsb + off); off = alignup(off + (size_t)(nd + 1) * 4);
    }
    for (int r = 0; r < 7; ++r) {
        csrs[r] = (int*)(wsb + off); off = alignup(off + (size_t)E[r] * 4);
    }
    for (int r = 0; r < 7; ++r) {
        ceas[r] = (uint2*)(wsb + off); off = alignup(off + (size_t)E[r] * 8);
    }

    // ---- preamble: hist + weight prep ----
    PreCtx P;
    for (int r = 0; r < 7; ++r) { P.dst[r] = dst[r]; P.E[r] = E[r]; }
    P.deg = deg;
    for (int r = 0; r < 8; ++r) P.bOff[r] = bOff[r];
    P.hOff[0] = 0;
    for (int r = 0; r < 7; ++r)
        P.hOff[r + 1] = P.hOff[r] + imax(1, (E[r] + 1023) / 1024);
    P.W1 = W1; P.W2 = W2; P.wp = wprep; P.wlin = wlin;
    for (int t = 0; t < 3; ++t) P.linW[t] = linW[t];
    P.gEnd = P.hOff[7] + 256;

    hipMemsetAsync(deg, 0, (size_t)bOff[7] * 256 * 4, stream);
    k_pre<<<P.gEnd, 256, 0, stream>>>(P);

    // ---- MFMA input embedding ----
    InCtx I;
    int ig = 0;
    for (int t = 0; t < 3; ++t) {
        I.x[t] = xin[t]; I.linb[t] = linb[t];
        I.hb[t] = hb + (size_t)noff[t] * H; I.n[t] = NSn[t];
        ig += (NSn[t] + 127) / 128;
        I.gend[t] = ig;
    }
    k_input_mfma<<<ig, 512, 0, stream>>>(I, wlin);

    // ---- CSR scans + scatter ----
    CsrCtx C;
    for (int r = 0; r < 7; ++r) {
        C.src[r] = src[r]; C.dst[r] = dst[r]; C.ea[r] = ea[r];
        C.csr_src[r] = csrs[r]; C.csr_ea[r] = ceas[r]; C.ptr[r] = ptrs[r];
        C.nd[r] = NSn[DST_T_[r]];
    }
    C.deg = deg; C.cursor = cursor; C.bsum = bsum;
    for (int r = 0; r < 8; ++r) { C.eOff[r] = eOff[r]; C.bOff[r] = bOff[r]; }

    k_scan_partial_all<<<bOff[7], 256, 0, stream>>>(C);
    k_scan_mid_all<<<7, 512, 0, stream>>>(C);
    k_scan_final_all<<<bOff[7], 256, 0, stream>>>(C);
    k_scatter_all<<<imin((Etot + 255) / 256, 8192), 256, 0, stream>>>(C, Etot);

    // ---- agg context ----
    AggCtx A;
    for (int r = 0; r < 7; ++r) {
        A.ptr[r] = ptrs[r]; A.csr_src[r] = csrs[r]; A.csr_ea[r] = ceas[r];
        A.hsrc[r] = hb + (size_t)noff[SRC_T_[r]] * H;
        A.hdst[r] = hb + (size_t)noff[DST_T_[r]] * H;
        A.z[r] = zb[r];
        A.nd[r] = NSn[DST_T_[r]];
    }
    for (int r = 0; r < 8; ++r) A.gOff[r] = gOff[r];

    // ---- mlp context ----
    static const int RELS[3][3] = {{0, 2, 0}, {1, 3, 5}, {4, 6, 0}};
    static const int NRELS[3] = {2, 3, 2};
    MlpCtx M;
    int gend = 0;
    for (int t = 0; t < 3; ++t) {
        M.nrel[t] = NRELS[t];
        M.noffH[t] = noff[t] * H;
        M.n[t] = NSn[t];
        gend += (NSn[t] + 127) / 128;
        M.gend[t] = gend;
        for (int k = 0; k < 3; ++k) M.z[t][k] = zb[RELS[t][k]];
    }

    // ---- layers ----
    for (int l = 0; l < 3; ++l) {
        const int fin = (l == 2) ? 1 : 0;
        k_aggz_all<<<gOff[7], 256, 0, stream>>>(A, eW, ebp, l);
        for (int t = 0; t < 3; ++t)
            for (int k = 0; k < 3; ++k) M.lr[t][k] = l * 7 + RELS[t][k];
        k_mlp_all<<<M.gend[2], 512, 0, stream>>>(
            M, hb, hb, fout, wprep, b1, g1, be1, b2, fin);
    }
}